// Round 1
// baseline (122.871 us; speedup 1.0000x reference)
//
#include <hip/hip_runtime.h>
#include <math.h>

#define EPSF 1e-5f
#define SINKHORN_ITERS 20
#define C_DIM 4096
#define N_DIM 4

// Kernel 1: tiny prep — sigmoids + sinkhorn on 4x4. params layout:
// [0..3] = sigmoid(H_pre), [4..7] = 2*sigmoid(H_post), [8..23] = M row-major.
__global__ void prep_kernel(const float* __restrict__ H_pre,
                            const float* __restrict__ H_post,
                            const float* __restrict__ H_res,
                            float* __restrict__ params) {
    if (threadIdx.x != 0 || blockIdx.x != 0) return;
    float M[4][4];
    for (int i = 0; i < 4; ++i)
        for (int j = 0; j < 4; ++j)
            M[i][j] = expf(H_res[i * 4 + j]);
    for (int it = 0; it < SINKHORN_ITERS; ++it) {
        // row normalize (sum over axis=1)
        for (int i = 0; i < 4; ++i) {
            float s = M[i][0] + M[i][1] + M[i][2] + M[i][3] + EPSF;
            M[i][0] /= s; M[i][1] /= s; M[i][2] /= s; M[i][3] /= s;
        }
        // col normalize (sum over axis=0)
        for (int j = 0; j < 4; ++j) {
            float s = M[0][j] + M[1][j] + M[2][j] + M[3][j] + EPSF;
            M[0][j] /= s; M[1][j] /= s; M[2][j] /= s; M[3][j] /= s;
        }
    }
    for (int i = 0; i < 4; ++i) {
        params[i]     = 1.0f / (1.0f + expf(-H_pre[i]));
        params[4 + i] = 2.0f / (1.0f + expf(-H_post[i]));
    }
    for (int i = 0; i < 4; ++i)
        for (int j = 0; j < 4; ++j)
            params[8 + i * 4 + j] = M[i][j];
}

// Kernel 2: one block per batch row b. Each thread owns 4 consecutive columns
// (float4) across all 4 expansion rows; x is read once, held in registers.
__global__ __launch_bounds__(1024)
void fused_kernel(const float* __restrict__ x,
                  const float* __restrict__ w,
                  const float* __restrict__ params,
                  float* __restrict__ out) {
    const int b = blockIdx.x;
    const int t = threadIdx.x;

    __shared__ float s_params[24];
    __shared__ float s_partial[16];
    __shared__ float s_inv;

    if (t < 24) s_params[t] = params[t];
    __syncthreads();

    const size_t row_base = (size_t)b * (N_DIM * C_DIM);
    const int c0 = t * 4;

    // Load x[b, i, c0..c0+3] for i = 0..3 (coalesced float4 per row)
    float4 x0 = *reinterpret_cast<const float4*>(x + row_base + 0 * C_DIM + c0);
    float4 x1 = *reinterpret_cast<const float4*>(x + row_base + 1 * C_DIM + c0);
    float4 x2 = *reinterpret_cast<const float4*>(x + row_base + 2 * C_DIM + c0);
    float4 x3 = *reinterpret_cast<const float4*>(x + row_base + 3 * C_DIM + c0);
    float4 w4 = *reinterpret_cast<const float4*>(w + c0);

    const float p0 = s_params[0], p1 = s_params[1], p2 = s_params[2], p3 = s_params[3];

    float4 agg;
    agg.x = p0 * x0.x + p1 * x1.x + p2 * x2.x + p3 * x3.x;
    agg.y = p0 * x0.y + p1 * x1.y + p2 * x2.y + p3 * x3.y;
    agg.z = p0 * x0.z + p1 * x1.z + p2 * x2.z + p3 * x3.z;
    agg.w = p0 * x0.w + p1 * x1.w + p2 * x2.w + p3 * x3.w;

    float ss = agg.x * agg.x + agg.y * agg.y + agg.z * agg.z + agg.w * agg.w;

    // wave64 reduce
    for (int off = 32; off > 0; off >>= 1)
        ss += __shfl_down(ss, off, 64);
    const int wid = t >> 6;
    const int lane = t & 63;
    if (lane == 0) s_partial[wid] = ss;
    __syncthreads();
    if (t == 0) {
        float tot = 0.0f;
        for (int k = 0; k < 16; ++k) tot += s_partial[k];
        s_inv = 1.0f / sqrtf(tot * (1.0f / (float)C_DIM) + EPSF);
    }
    __syncthreads();
    const float inv = s_inv;

    // normed * w (shared across the 4 output rows)
    float4 nw;
    nw.x = agg.x * inv * w4.x;
    nw.y = agg.y * inv * w4.y;
    nw.z = agg.z * inv * w4.z;
    nw.w = agg.w * inv * w4.w;

    #pragma unroll
    for (int i = 0; i < 4; ++i) {
        const float m0 = s_params[8 + i * 4 + 0];
        const float m1 = s_params[8 + i * 4 + 1];
        const float m2 = s_params[8 + i * 4 + 2];
        const float m3 = s_params[8 + i * 4 + 3];
        const float po = s_params[4 + i];
        float4 o;
        o.x = m0 * x0.x + m1 * x1.x + m2 * x2.x + m3 * x3.x + po * nw.x;
        o.y = m0 * x0.y + m1 * x1.y + m2 * x2.y + m3 * x3.y + po * nw.y;
        o.z = m0 * x0.z + m1 * x1.z + m2 * x2.z + m3 * x3.z + po * nw.z;
        o.w = m0 * x0.w + m1 * x1.w + m2 * x2.w + m3 * x3.w + po * nw.w;
        *reinterpret_cast<float4*>(out + row_base + i * C_DIM + c0) = o;
    }
}

extern "C" void kernel_launch(void* const* d_in, const int* in_sizes, int n_in,
                              void* d_out, int out_size, void* d_ws, size_t ws_size,
                              hipStream_t stream) {
    const float* x      = (const float*)d_in[0];
    const float* w      = (const float*)d_in[1];
    const float* H_pre  = (const float*)d_in[2];
    const float* H_post = (const float*)d_in[3];
    const float* H_res  = (const float*)d_in[4];
    float* out    = (float*)d_out;
    float* params = (float*)d_ws;

    const int B = in_sizes[0] / (N_DIM * C_DIM);  // 4096

    prep_kernel<<<1, 64, 0, stream>>>(H_pre, H_post, H_res, params);
    fused_kernel<<<B, 1024, 0, stream>>>(x, w, params, out);
}

// Round 2
// 113.873 us; speedup vs baseline: 1.0790x; 1.0790x over previous
//
#include <hip/hip_runtime.h>
#include <math.h>

#define EPSF 1e-5f
#define SINKHORN_ITERS 20
#define C_DIM 4096
#define N_DIM 4

typedef __attribute__((ext_vector_type(4))) float fx4;

// Kernel 1: tiny prep — sigmoids + sinkhorn on 4x4. params layout:
// [0..3] = sigmoid(H_pre), [4..7] = 2*sigmoid(H_post), [8..23] = M row-major.
__global__ void prep_kernel(const float* __restrict__ H_pre,
                            const float* __restrict__ H_post,
                            const float* __restrict__ H_res,
                            float* __restrict__ params) {
    if (threadIdx.x != 0 || blockIdx.x != 0) return;
    float M[4][4];
    for (int i = 0; i < 4; ++i)
        for (int j = 0; j < 4; ++j)
            M[i][j] = expf(H_res[i * 4 + j]);
    for (int it = 0; it < SINKHORN_ITERS; ++it) {
        for (int i = 0; i < 4; ++i) {       // row normalize (axis=1)
            float s = M[i][0] + M[i][1] + M[i][2] + M[i][3] + EPSF;
            M[i][0] /= s; M[i][1] /= s; M[i][2] /= s; M[i][3] /= s;
        }
        for (int j = 0; j < 4; ++j) {       // col normalize (axis=0)
            float s = M[0][j] + M[1][j] + M[2][j] + M[3][j] + EPSF;
            M[0][j] /= s; M[1][j] /= s; M[2][j] /= s; M[3][j] /= s;
        }
    }
    for (int i = 0; i < 4; ++i) {
        params[i]     = 1.0f / (1.0f + expf(-H_pre[i]));
        params[4 + i] = 2.0f / (1.0f + expf(-H_post[i]));
    }
    for (int i = 0; i < 4; ++i)
        for (int j = 0; j < 4; ++j)
            params[8 + i * 4 + j] = M[i][j];
}

// Kernel 2: one block (256 threads, 4 waves) per batch row b.
// Thread t owns columns {k*1024 + t*4 .. +3} for k=0..3, all 4 expansion rows
// held in registers (x read exactly once). Single __syncthreads for the RMS
// reduce. Params come in via uniform scalar loads (no LDS staging).
__global__ __launch_bounds__(256, 4)
void fused_kernel(const float* __restrict__ x,
                  const float* __restrict__ w,
                  const float* __restrict__ params,
                  float* __restrict__ out) {
    const int b = blockIdx.x;
    const int t = threadIdx.x;

    // uniform indices -> scalar (s_load) broadcast
    const float p0 = params[0], p1 = params[1], p2 = params[2], p3 = params[3];

    const size_t base = (size_t)b * (N_DIM * C_DIM);
    const int c0 = t * 4;

    // Load x[b, i, k*1024 + c0 .. +3] — 16 float4 in flight, nontemporal.
    fx4 xv[4][4];   // [row i][chunk k]
    #pragma unroll
    for (int i = 0; i < 4; ++i)
        #pragma unroll
        for (int k = 0; k < 4; ++k)
            xv[i][k] = __builtin_nontemporal_load(
                reinterpret_cast<const fx4*>(x + base + i * C_DIM + k * 1024 + c0));

    // aggregate + sum of squares (agg recomputed later; only ss kept)
    float ss = 0.0f;
    #pragma unroll
    for (int k = 0; k < 4; ++k) {
        fx4 a = p0 * xv[0][k] + p1 * xv[1][k] + p2 * xv[2][k] + p3 * xv[3][k];
        ss += a.x * a.x + a.y * a.y + a.z * a.z + a.w * a.w;
    }

    // wave64 reduce -> 4 partials -> every thread sums them (one barrier)
    #pragma unroll
    for (int off = 32; off > 0; off >>= 1)
        ss += __shfl_down(ss, off, 64);
    __shared__ float sp[4];
    if ((t & 63) == 0) sp[t >> 6] = ss;
    __syncthreads();
    const float tot = sp[0] + sp[1] + sp[2] + sp[3];
    const float inv = 1.0f / sqrtf(tot * (1.0f / (float)C_DIM) + EPSF);

    // output: out[b,i,c] = sum_j M[i][j] x[b,j,c] + post_i * (agg*inv*w)
    #pragma unroll
    for (int k = 0; k < 4; ++k) {
        fx4 wv = *reinterpret_cast<const fx4*>(w + k * 1024 + c0);  // L2-hot
        fx4 a = p0 * xv[0][k] + p1 * xv[1][k] + p2 * xv[2][k] + p3 * xv[3][k];
        fx4 nw = a * inv * wv;
        #pragma unroll
        for (int i = 0; i < 4; ++i) {
            const float m0 = params[8 + i * 4 + 0];
            const float m1 = params[8 + i * 4 + 1];
            const float m2 = params[8 + i * 4 + 2];
            const float m3 = params[8 + i * 4 + 3];
            const float po = params[4 + i];
            fx4 o = m0 * xv[0][k] + m1 * xv[1][k] + m2 * xv[2][k] + m3 * xv[3][k]
                  + po * nw;
            __builtin_nontemporal_store(
                o, reinterpret_cast<fx4*>(out + base + i * C_DIM + k * 1024 + c0));
        }
    }
}

extern "C" void kernel_launch(void* const* d_in, const int* in_sizes, int n_in,
                              void* d_out, int out_size, void* d_ws, size_t ws_size,
                              hipStream_t stream) {
    const float* x      = (const float*)d_in[0];
    const float* w      = (const float*)d_in[1];
    const float* H_pre  = (const float*)d_in[2];
    const float* H_post = (const float*)d_in[3];
    const float* H_res  = (const float*)d_in[4];
    float* out    = (float*)d_out;
    float* params = (float*)d_ws;

    const int B = in_sizes[0] / (N_DIM * C_DIM);  // 4096

    prep_kernel<<<1, 64, 0, stream>>>(H_pre, H_post, H_res, params);
    fused_kernel<<<B, 256, 0, stream>>>(x, w, params, out);
}